// Round 5
// baseline (2114.823 us; speedup 1.0000x reference)
//
#include <hip/hip_runtime.h>
#include <math.h>

#define B_   256
#define S_   160
#define E_   300
#define H_   256
#define T_   200
#define G4H  1024
#define CH   16
#define NCH  10

typedef float  f32x4  __attribute__((ext_vector_type(4)));
typedef __bf16 bf16x4 __attribute__((ext_vector_type(4)));
typedef __bf16 bf16x8 __attribute__((ext_vector_type(8)));

__device__ __forceinline__ float sigf(float x) {
    float e = expf(-fabsf(x));
    float p = 1.0f / (1.0f + e);
    return x >= 0.0f ? p : e * p;
}

// 4 consecutive K-values from concatenated [first(300) | second(200) | pad] row
__device__ __forceinline__ float4 pick4(const float* __restrict__ e,
                                        const float* __restrict__ k, int kg) {
    if (kg < E_)      return *(const float4*)(e + kg);
    if (kg < E_ + T_) return *(const float4*)(k + (kg - E_));
    return make_float4(0.f, 0.f, 0.f, 0.f);
}

__device__ __forceinline__ void split4(float4 v, bf16x4& h, bf16x4& l) {
    h[0] = (__bf16)v.x; l[0] = (__bf16)(v.x - (float)h[0]);
    h[1] = (__bf16)v.y; l[1] = (__bf16)(v.y - (float)h[1]);
    h[2] = (__bf16)v.z; l[2] = (__bf16)(v.z - (float)h[2]);
    h[3] = (__bf16)v.w; l[3] = (__bf16)(v.w - (float)h[3]);
}

// ---------------------------------------------------------------------------
// Input GEMM: split-bf16 MFMA, tile 128x128, BK=32, now software-pipelined:
// raw float4 loads for iter kt+1 are issued before MFMA(kt).
// ---------------------------------------------------------------------------
__global__ __launch_bounds__(256, 2) void gemm_g2(
    const int* __restrict__ x1, const int* __restrict__ x2,
    const float* __restrict__ key_c, const float* __restrict__ key_r,
    const float* __restrict__ emb, const float* __restrict__ Wih,
    const float* __restrict__ Wkh, const float* __restrict__ bg,
    float* __restrict__ G, int s0)
{
    __shared__ __align__(16) __bf16 Ah[128 * 32];
    __shared__ __align__(16) __bf16 Al[128 * 32];
    __shared__ __align__(16) __bf16 Bh[128 * 32];
    __shared__ __align__(16) __bf16 Bl[128 * 32];

    const int t   = threadIdx.x;
    const int rnn = blockIdx.z;
    const int m0  = blockIdx.x * 128;
    const int n0  = blockIdx.y * 128;
    const int* xx = rnn ? x2 : x1;
    const float* key = rnn ? key_r : key_c;

    const int r0  = t >> 3;
    const int kq  = t & 7;
    const int csw = (((kq >> 1) ^ ((r0 >> 1) & 3)) * 16) + (kq & 1) * 8;

    const float* aeb[4]; const float* akb[4];
    const float* wv1[4]; const float* wv2[4];
    #pragma unroll
    for (int i = 0; i < 4; ++i) {
        const int row = r0 + 32 * i;
        const int am  = m0 + row;
        const int bs  = (am >> 4) * S_ + s0 + (am & 15);
        aeb[i] = emb + (size_t)xx[bs] * E_;
        akb[i] = key + (size_t)bs * T_;
        const int n = n0 + row;
        wv1[i] = Wih + (size_t)n * E_;
        wv2[i] = Wkh + (size_t)n * T_;
    }

    const int w  = t >> 6;
    const int wm = w >> 1;
    const int wn = w & 1;
    const int l  = t & 63;
    const int cl = l & 15;
    const int ch = l >> 4;
    const int chs = ((ch ^ ((cl >> 1) & 3)) * 16);

    f32x4 acc[4][4];
    #pragma unroll
    for (int fm = 0; fm < 4; ++fm)
        #pragma unroll
        for (int fn = 0; fn < 4; ++fn) acc[fm][fn] = (f32x4){0.f, 0.f, 0.f, 0.f};

    float4 va[4], vb[4];
    {
        const int kg = kq * 4;
        #pragma unroll
        for (int i = 0; i < 4; ++i) {
            va[i] = pick4(aeb[i], akb[i], kg);
            vb[i] = pick4(wv1[i], wv2[i], kg);
        }
    }

    for (int kt = 0; kt < 16; ++kt) {
        bf16x4 sAh[4], sAl[4], sBh[4], sBl[4];
        #pragma unroll
        for (int i = 0; i < 4; ++i) {
            split4(va[i], sAh[i], sAl[i]);
            split4(vb[i], sBh[i], sBl[i]);
        }
        __syncthreads();
        #pragma unroll
        for (int i = 0; i < 4; ++i) {
            const int off = (r0 + 32 * i) * 64 + csw;
            *(bf16x4*)((char*)Ah + off) = sAh[i];
            *(bf16x4*)((char*)Al + off) = sAl[i];
            *(bf16x4*)((char*)Bh + off) = sBh[i];
            *(bf16x4*)((char*)Bl + off) = sBl[i];
        }
        __syncthreads();

        if (kt < 15) {  // prefetch next k-tile; completes under the MFMAs
            const int kg = (kt + 1) * 32 + kq * 4;
            #pragma unroll
            for (int i = 0; i < 4; ++i) {
                va[i] = pick4(aeb[i], akb[i], kg);
                vb[i] = pick4(wv1[i], wv2[i], kg);
            }
        }

        bf16x8 fBh[4], fBl[4];
        #pragma unroll
        for (int fn = 0; fn < 4; ++fn) {
            const int off = (wn * 64 + fn * 16 + cl) * 64 + chs;
            fBh[fn] = *(const bf16x8*)((const char*)Bh + off);
            fBl[fn] = *(const bf16x8*)((const char*)Bl + off);
        }
        #pragma unroll
        for (int fm = 0; fm < 4; ++fm) {
            const int off = (wm * 64 + fm * 16 + cl) * 64 + chs;
            const bf16x8 fAh = *(const bf16x8*)((const char*)Ah + off);
            const bf16x8 fAl = *(const bf16x8*)((const char*)Al + off);
            #pragma unroll
            for (int fn = 0; fn < 4; ++fn) {
                acc[fm][fn] = __builtin_amdgcn_mfma_f32_16x16x32_bf16(fAh, fBh[fn], acc[fm][fn], 0, 0, 0);
                acc[fm][fn] = __builtin_amdgcn_mfma_f32_16x16x32_bf16(fAh, fBl[fn], acc[fm][fn], 0, 0, 0);
                acc[fm][fn] = __builtin_amdgcn_mfma_f32_16x16x32_bf16(fAl, fBh[fn], acc[fm][fn], 0, 0, 0);
            }
        }
    }

    float bgl[4];
    #pragma unroll
    for (int fn = 0; fn < 4; ++fn) bgl[fn] = bg[n0 + wn * 64 + fn * 16 + cl];

    #pragma unroll
    for (int fm = 0; fm < 4; ++fm) {
        #pragma unroll
        for (int r = 0; r < 4; ++r) {
            const int m  = m0 + wm * 64 + fm * 16 + ch * 4 + r;
            const int b  = m >> 4;
            const int sl = m & 15;
            float* rowp = G + ((size_t)(rnn * CH + sl) * B_ + b) * G4H;
            #pragma unroll
            for (int fn = 0; fn < 4; ++fn)
                rowp[n0 + wn * 64 + fn * 16 + cl] = acc[fm][fn][r] + bgl[fn];
        }
    }
}

// ---------------------------------------------------------------------------
// Split Whh (1024x256 fp32) into bf16 hi/lo planes.
// ---------------------------------------------------------------------------
__global__ __launch_bounds__(256) void whh_split(
    const float* __restrict__ W, __bf16* __restrict__ hi, __bf16* __restrict__ lo)
{
    const int i4 = (blockIdx.x * 256 + threadIdx.x) * 4;
    const float4 v = *(const float4*)(W + i4);
    bf16x4 h, l;
    split4(v, h, l);
    *(bf16x4*)(hi + i4) = h;
    *(bf16x4*)(lo + i4) = l;
}

// ---------------------------------------------------------------------------
// LSTM step, zero-LDS GEMM. Grid (16 mg, 16 ng, 2 rnn) = 512 blocks, 256 thr.
// Block tile: 16 batch rows x (4 gates x 16 j); wave w = gate w.
// A (h hi/lo) and B (Whh hi/lo) fragments loaded DIRECTLY from global in
// MFMA fragment layout (lane&15 -> row, lane>>4 -> 8-elem k-chunk); all loads
// + G + c issued at entry. 24 MFMA (8 ksub x 3 split passes, 3 acc chains).
// Tiny LDS (16x68 fp32) only for the cross-wave gate transpose.
// ---------------------------------------------------------------------------
__global__ __launch_bounds__(256, 2) void lstm_fused(
    const float* __restrict__ G,
    const __bf16* __restrict__ Whi, const __bf16* __restrict__ Wlo,
    const __bf16* __restrict__ hhi_in, const __bf16* __restrict__ hlo_in,
    __bf16* __restrict__ hhi_out, __bf16* __restrict__ hlo_out,
    float* __restrict__ cst, float* __restrict__ sc,
    int sl, int s_glob)
{
    __shared__ float gs[16][68];

    const int t   = threadIdx.x;
    const int m0  = blockIdx.x * 16;   // batch row base
    const int j0  = blockIdx.y * 16;   // j base
    const int rnn = blockIdx.z;

    const int w  = t >> 6;             // wave = gate
    const int l  = t & 63;
    const int cl = l & 15;
    const int ch = l >> 4;

    // fragment base offsets (elements)
    const size_t arow = (size_t)(rnn * 256 + m0 + cl) * 256 + ch * 8;
    const size_t brow = (size_t)(w * 256 + j0 + cl) * 256 + ch * 8;

    bf16x8 fAh[8], fAl[8], fBh[8], fBl[8];
    #pragma unroll
    for (int ks = 0; ks < 8; ++ks) {
        fAh[ks] = *(const bf16x8*)(hhi_in + arow + ks * 32);
        fAl[ks] = *(const bf16x8*)(hlo_in + arow + ks * 32);
        fBh[ks] = *(const bf16x8*)(Whi + brow + ks * 32);
        fBl[ks] = *(const bf16x8*)(Wlo + brow + ks * 32);
    }

    // epilogue operand prefetch (independent of the GEMM)
    const int m_e  = t >> 4;           // 0..15
    const int jj_e = t & 15;           // 0..15
    const int b_e  = m0 + m_e;
    const int j_e  = j0 + jj_e;
    const float* Gp = G + ((size_t)(rnn * CH + sl) * B_ + b_e) * G4H + j_e;
    const float Gi = Gp[0];
    const float Gf = Gp[256];
    const float Gg = Gp[512];
    const float Go = Gp[768];
    float* cp = cst + (size_t)(rnn * 256 + b_e) * 256 + j_e;
    const float c_in = *cp;

    f32x4 aHH = (f32x4){0.f, 0.f, 0.f, 0.f};
    f32x4 aHL = (f32x4){0.f, 0.f, 0.f, 0.f};
    f32x4 aLH = (f32x4){0.f, 0.f, 0.f, 0.f};
    #pragma unroll
    for (int ks = 0; ks < 8; ++ks) {
        aHH = __builtin_amdgcn_mfma_f32_16x16x32_bf16(fAh[ks], fBh[ks], aHH, 0, 0, 0);
        aHL = __builtin_amdgcn_mfma_f32_16x16x32_bf16(fAh[ks], fBl[ks], aHL, 0, 0, 0);
        aLH = __builtin_amdgcn_mfma_f32_16x16x32_bf16(fAl[ks], fBh[ks], aLH, 0, 0, 0);
    }
    const f32x4 acc = (aHH + aHL) + aLH;

    // cross-wave gate transpose: gs[m][gate*16 + jj]
    #pragma unroll
    for (int r = 0; r < 4; ++r)
        gs[ch * 4 + r][w * 16 + cl] = acc[r];
    __syncthreads();

    const float gi = gs[m_e][jj_e]      + Gi;
    const float gf = gs[m_e][16 + jj_e] + Gf;
    const float gg = gs[m_e][32 + jj_e] + Gg;
    const float go = gs[m_e][48 + jj_e] + Go;

    const float c = sigf(gf) * c_in + sigf(gi) * tanhf(gg);
    const float h = sigf(go) * tanhf(c);
    *cp = c;
    const __bf16 hh = (__bf16)h;
    const size_t ho = (size_t)(rnn * 256 + b_e) * 256 + j_e;
    hhi_out[ho] = hh;
    hlo_out[ho] = (__bf16)(h - (float)hh);
    if (rnn == 0) sc[((size_t)b_e * S_ + s_glob) * H_ + j_e] = h;
}

// ---------------------------------------------------------------------------
// Fused attention epilogue, one block per batch row b. r reconstructed from
// the rnn1 parity-0 h hi/lo planes.
// ---------------------------------------------------------------------------
__global__ __launch_bounds__(256) void final_kernel(
    const float* __restrict__ sc,
    const __bf16* __restrict__ rhi, const __bf16* __restrict__ rlo,
    const float* __restrict__ Wattn, const float* __restrict__ battn,
    const float* __restrict__ M, const float* __restrict__ bscal,
    const float* __restrict__ mask, float* __restrict__ out)
{
    __shared__ float rs[256], us[256], red[256], as_[256];
    const int b = blockIdx.x;
    const int t = threadIdx.x;

    const size_t ri = (size_t)(256 + b) * 256 + t;
    rs[t] = (float)rhi[ri] + (float)rlo[ri];
    __syncthreads();

    float acc = 0.0f;
    for (int h = 0; h < 256; ++h) acc += rs[h] * Wattn[h * 256 + t];
    us[t] = acc;

    red[t] = battn[t] * rs[t];
    __syncthreads();
    for (int off = 128; off; off >>= 1) {
        if (t < off) red[t] += red[t + off];
        __syncthreads();
    }
    float beta = red[0];
    __syncthreads();

    float vh = 0.0f;
    {
        const float* Mrow = M + t * 256;
        for (int k = 0; k < 256; ++k) vh += Mrow[k] * rs[k];
    }

    float e = -INFINITY;
    if (t < S_) {
        float d = 0.0f;
        const float* scrow = sc + ((size_t)b * S_ + t) * H_;
        for (int h = 0; h < 256; ++h) d += scrow[h] * us[h];
        e = (d + beta) * mask[b * S_ + t];
    }
    red[t] = e;
    __syncthreads();
    for (int off = 128; off; off >>= 1) {
        if (t < off) red[t] = fmaxf(red[t], red[t + off]);
        __syncthreads();
    }
    float mx = red[0];
    __syncthreads();

    float p = (t < S_) ? expf(e - mx) : 0.0f;
    as_[t] = p;
    red[t] = p;
    __syncthreads();
    for (int off = 128; off; off >>= 1) {
        if (t < off) red[t] += red[t + off];
        __syncthreads();
    }
    float inv = 1.0f / red[0];
    __syncthreads();

    float ca = 0.0f;
    for (int s = 0; s < S_; ++s) ca += as_[s] * sc[((size_t)b * S_ + s) * H_ + t];
    ca *= inv;

    red[t] = ca * vh;
    __syncthreads();
    for (int off = 128; off; off >>= 1) {
        if (t < off) red[t] += red[t + off];
        __syncthreads();
    }
    if (t == 0) out[b] = red[0] + bscal[0];
}

// ---------------------------------------------------------------------------
extern "C" void kernel_launch(void* const* d_in, const int* in_sizes, int n_in,
                              void* d_out, int out_size, void* d_ws, size_t ws_size,
                              hipStream_t stream)
{
    const int*   x1    = (const int*)d_in[0];
    const int*   x2    = (const int*)d_in[1];
    const float* mask  = (const float*)d_in[2];
    const float* key_c = (const float*)d_in[3];
    const float* key_r = (const float*)d_in[4];
    const float* emb   = (const float*)d_in[5];
    const float* Wih   = (const float*)d_in[6];
    const float* Whh   = (const float*)d_in[7];
    const float* Wkh   = (const float*)d_in[8];
    const float* bg    = (const float*)d_in[9];
    const float* Wattn = (const float*)d_in[10];
    const float* battn = (const float*)d_in[11];
    const float* M     = (const float*)d_in[12];
    const float* bb    = (const float*)d_in[13];
    float* out = (float*)d_out;
    char*  wsb = (char*)d_ws;

    // byte layout
    float*  G    = (float*)(wsb + 0);            // 33,554,432 B
    float*  sc   = (float*)(wsb + 33554432);     // 41,943,040 B
    float*  cst  = (float*)(wsb + 75497472);     //    524,288 B
    __bf16* hhi0 = (__bf16*)(wsb + 76021760);    //    262,144 B
    __bf16* hlo0 = (__bf16*)(wsb + 76283904);
    __bf16* hhi1 = (__bf16*)(wsb + 76546048);
    __bf16* hlo1 = (__bf16*)(wsb + 76808192);
    __bf16* Whi  = (__bf16*)(wsb + 77070336);    //    524,288 B
    __bf16* Wlo  = (__bf16*)(wsb + 77594624);
    if (ws_size < 78118912) return;  // fail visibly if workspace too small

    // zero c + parity-0 h planes (contiguous 1 MB)
    hipMemsetAsync(wsb + 75497472, 0, 1048576, stream);
    whh_split<<<dim3(256), 256, 0, stream>>>(Whh, Whi, Wlo);

    int cur = 0;
    for (int ci = 0; ci < NCH; ++ci) {
        gemm_g2<<<dim3(32, 8, 2), 256, 0, stream>>>(x1, x2, key_c, key_r, emb,
                                                    Wih, Wkh, bg, G, ci * CH);
        for (int slq = 0; slq < CH; ++slq) {
            const int tstep = ci * CH + slq;
            __bf16* hi_in  = cur ? hhi1 : hhi0;
            __bf16* lo_in  = cur ? hlo1 : hlo0;
            __bf16* hi_out = cur ? hhi0 : hhi1;
            __bf16* lo_out = cur ? hlo0 : hlo1;
            lstm_fused<<<dim3(16, 16, 2), 256, 0, stream>>>(G, Whi, Wlo,
                                                            hi_in, lo_in, hi_out, lo_out,
                                                            cst, sc, slq, tstep);
            cur ^= 1;
        }
    }

    // after 160 steps the last write parity is buffer 0; r = rnn1 rows
    final_kernel<<<dim3(256), 256, 0, stream>>>(sc, hhi0, hlo0, Wattn, battn,
                                                M, bb, mask, out);
}